// Round 3
// baseline (234.935 us; speedup 1.0000x reference)
//
#include <hip/hip_runtime.h>
#include <hip/hip_bf16.h>

#define B_   8
#define S_   1024
#define H_   768
#define NH_  12
#define DK_  64
#define M_   (B_ * S_)   // 8192

typedef __attribute__((ext_vector_type(8))) short          short8;
typedef __attribute__((ext_vector_type(8))) unsigned short ushort8;
typedef __attribute__((ext_vector_type(4))) unsigned short ushort4v;
typedef __attribute__((ext_vector_type(4))) float          f32x4;

__device__ __forceinline__ unsigned short f2bf(float x) {
    union { float f; unsigned u; } v; v.f = x;
    unsigned r = v.u + 0x7FFFu + ((v.u >> 16) & 1u);
    return (unsigned short)(r >> 16);
}

// ---------------------------------------------------------------------------
// fp32 -> bf16 convert (memory-bound), optional scale. 4 elements/thread.
// ---------------------------------------------------------------------------
__global__ __launch_bounds__(256)
void cvt_bf16(const float* __restrict__ in, unsigned short* __restrict__ out,
              int n4, float scale)
{
    const int i = blockIdx.x * blockDim.x + threadIdx.x;
    if (i >= n4) return;
    const float4 x = ((const float4*)in)[i];
    ushort4v o;
    o[0] = f2bf(x.x * scale); o[1] = f2bf(x.y * scale);
    o[2] = f2bf(x.z * scale); o[3] = f2bf(x.w * scale);
    ((ushort4v*)out)[i] = o;
}

// ---------------------------------------------------------------------------
// m97-structure GEMM: y[M,N] = x[M,K] @ W[N,K]^T, all-bf16 inputs.
// 128x128 tile, BK=32, global_load_lds(16B), 4 waves x (4x4) 16x16 frags.
// ---------------------------------------------------------------------------
template<bool OUT_BF16>
__global__ __launch_bounds__(256)
void gemm_bt(const unsigned short* __restrict__ A,
             const unsigned short* __restrict__ Bw,
             void* __restrict__ C, int M, int N, int K)
{
    __shared__ unsigned short As[128 * 32];   // 8 KB, linear [row][32]
    __shared__ unsigned short Bs[128 * 32];

    const int tid  = threadIdx.x;
    const int w    = tid >> 6, lane = tid & 63;
    const int lg   = lane >> 4, lc = lane & 15;
    const int bm   = blockIdx.x, bn = blockIdx.y;
    const int wm   = (w >> 1) * 64, wn = (w & 1) * 64;
    const int srow = lane >> 2, scol = (lane & 3) * 8;

    // wave w stages chunks c = w*2+i (16 rows each) of both tiles
    const unsigned short* gA = &A [(size_t)(bm * 128 + w * 32 + srow) * K + scol];
    const unsigned short* gB = &Bw[(size_t)(bn * 128 + w * 32 + srow) * K + scol];

    f32x4 acc[4][4] = {};

    for (int k0 = 0; k0 < K; k0 += 32) {
#pragma unroll
        for (int i = 0; i < 2; i++) {
            __builtin_amdgcn_global_load_lds(
                (const __attribute__((address_space(1))) unsigned int*)(gA + (size_t)i * 16 * K + k0),
                (__attribute__((address_space(3))) unsigned int*)&As[(w * 2 + i) * 512],
                16, 0, 0);
            __builtin_amdgcn_global_load_lds(
                (const __attribute__((address_space(1))) unsigned int*)(gB + (size_t)i * 16 * K + k0),
                (__attribute__((address_space(3))) unsigned int*)&Bs[(w * 2 + i) * 512],
                16, 0, 0);
        }
        __syncthreads();

        short8 af[4], bfr[4];
#pragma unroll
        for (int mi = 0; mi < 4; mi++)
            af[mi] = *(const short8*)&As[(wm + mi * 16 + lc) * 32 + lg * 8];
#pragma unroll
        for (int ni = 0; ni < 4; ni++)
            bfr[ni] = *(const short8*)&Bs[(wn + ni * 16 + lc) * 32 + lg * 8];
#pragma unroll
        for (int mi = 0; mi < 4; mi++)
#pragma unroll
            for (int ni = 0; ni < 4; ni++)
                acc[mi][ni] = __builtin_amdgcn_mfma_f32_16x16x32_bf16(
                    af[mi], bfr[ni], acc[mi][ni], 0, 0, 0);
        __syncthreads();
    }

#pragma unroll
    for (int mi = 0; mi < 4; mi++)
#pragma unroll
        for (int ni = 0; ni < 4; ni++)
#pragma unroll
            for (int reg = 0; reg < 4; reg++) {
                const int row = bm * 128 + wm + mi * 16 + lg * 4 + reg;
                const int col = bn * 128 + wn + ni * 16 + lc;
                if (OUT_BF16)
                    ((unsigned short*)C)[(size_t)row * N + col] = f2bf(acc[mi][ni][reg]);
                else
                    ((float*)C)[(size_t)row * N + col] = acc[mi][ni][reg];
            }
}

// ---------------------------------------------------------------------------
// Flash attention: 1 block = (b, head, 64-row q tile). 4 waves x 16 q-rows.
// Q pre-scaled by log2(e)/sqrt(DK) in the Wq convert -> scores already in
// exp2 domain. T13 defer-rescale (THR=8). XOR-swizzled V^T and P buffers.
// ---------------------------------------------------------------------------
__global__ __launch_bounds__(256)
void attn(const unsigned short* __restrict__ q,
          const unsigned short* __restrict__ k,
          const unsigned short* __restrict__ v,
          unsigned short* __restrict__ c)
{
    __shared__ unsigned short Ks[64][72];
    __shared__ unsigned short Vt[64][72];   // Vt[d][key ^ ((d>>4)<<4)]
    __shared__ unsigned short Ps[64][72];   // staging for Q, then P tiles

    const int tid  = threadIdx.x;
    const int qt   = blockIdx.x, h = blockIdx.y, b = blockIdx.z;
    const int wid  = tid >> 6;
    const int lane = tid & 63;
    const int lg   = lane >> 4, lc = lane & 15;
    const int r    = tid >> 2;
    const int d0   = (tid & 3) * 16;
    const int g    = tid & 3;
    const size_t base = (size_t)b * S_ * H_ + (size_t)h * DK_;

    {
        const unsigned short* src = &q[base + (size_t)(qt * 64 + r) * H_ + d0];
        *(ushort8*)&Ps[r][d0]     = *(const ushort8*)src;
        *(ushort8*)&Ps[r][d0 + 8] = *(const ushort8*)(src + 8);
    }
    __syncthreads();
    short8 aq[2];
#pragma unroll
    for (int ks = 0; ks < 2; ks++)
        aq[ks] = *(const short8*)&Ps[wid * 16 + lc][ks * 32 + lg * 8];

    f32x4 o[4] = {};
    float mrow[4], lrow[4];
#pragma unroll
    for (int i = 0; i < 4; i++) { mrow[i] = -1e30f; lrow[i] = 0.f; }

    for (int kt = 0; kt < S_ / 64; kt++) {
        {
            const unsigned short* ksrc = &k[base + (size_t)(kt * 64 + r) * H_ + d0];
            *(ushort8*)&Ks[r][d0]     = *(const ushort8*)ksrc;
            *(ushort8*)&Ks[r][d0 + 8] = *(const ushort8*)(ksrc + 8);
            const unsigned short* vsrc = &v[base + (size_t)(kt * 64 + r) * H_ + d0];
            const ushort8 v0 = *(const ushort8*)vsrc;
            const ushort8 v1 = *(const ushort8*)(vsrc + 8);
            const int colv = r ^ (g << 4);
#pragma unroll
            for (int j = 0; j < 8; j++) Vt[d0 + j][colv]     = v0[j];
#pragma unroll
            for (int j = 0; j < 8; j++) Vt[d0 + 8 + j][colv] = v1[j];
        }
        __syncthreads();

        // S = Q K^T (already exp2-domain scaled via Wq)
        f32x4 s[4] = {};
#pragma unroll
        for (int ni = 0; ni < 4; ni++)
#pragma unroll
            for (int ks = 0; ks < 2; ks++) {
                const short8 bk = *(const short8*)&Ks[ni * 16 + lc][ks * 32 + lg * 8];
                s[ni] = __builtin_amdgcn_mfma_f32_16x16x32_bf16(aq[ks], bk, s[ni], 0, 0, 0);
            }

        // per-row max (rows at lg*4+reg, key-cols at ni*16+lc)
        float pmax[4];
#pragma unroll
        for (int reg = 0; reg < 4; reg++) {
            float pm = fmaxf(fmaxf(s[0][reg], s[1][reg]), fmaxf(s[2][reg], s[3][reg]));
#pragma unroll
            for (int d = 1; d < 16; d <<= 1)
                pm = fmaxf(pm, __shfl_xor(pm, d, 64));
            pmax[reg] = pm;
        }

        // T13: rescale only when some row's max grew by > 8 (wave-uniform)
        const bool grow = (pmax[0] > mrow[0] + 8.f) | (pmax[1] > mrow[1] + 8.f) |
                          (pmax[2] > mrow[2] + 8.f) | (pmax[3] > mrow[3] + 8.f);
        if (__any(grow)) {
#pragma unroll
            for (int reg = 0; reg < 4; reg++) {
                const float mnew  = fmaxf(mrow[reg], pmax[reg]);
                const float scale = exp2f(mrow[reg] - mnew);
                lrow[reg] *= scale;
                mrow[reg]  = mnew;
                o[0][reg] *= scale; o[1][reg] *= scale;
                o[2][reg] *= scale; o[3][reg] *= scale;
            }
        }

#pragma unroll
        for (int reg = 0; reg < 4; reg++) {
            float psum = 0.f;
#pragma unroll
            for (int ni = 0; ni < 4; ni++) {
                const float p = exp2f(s[ni][reg] - mrow[reg]);
                s[ni][reg] = p; psum += p;
            }
#pragma unroll
            for (int d = 1; d < 16; d <<= 1)
                psum += __shfl_xor(psum, d, 64);
            lrow[reg] += psum;
        }

        // P -> LDS, swizzled; wave-local region
#pragma unroll
        for (int ni = 0; ni < 4; ni++)
#pragma unroll
            for (int reg = 0; reg < 4; reg++)
                Ps[wid * 16 + lg * 4 + reg][(ni * 16 + lc) ^ (lg << 4)] =
                    f2bf(s[ni][reg]);

        short8 pa[2];
#pragma unroll
        for (int ks = 0; ks < 2; ks++)
            pa[ks] = *(const short8*)
                &Ps[wid * 16 + lc][(ks * 32 + lg * 8) ^ ((lc >> 2) << 4)];
#pragma unroll
        for (int ni = 0; ni < 4; ni++)
#pragma unroll
            for (int ks = 0; ks < 2; ks++) {
                const short8 bv = *(const short8*)
                    &Vt[ni * 16 + lc][(ks * 32 + lg * 8) ^ (ni << 4)];
                o[ni] = __builtin_amdgcn_mfma_f32_16x16x32_bf16(pa[ks], bv, o[ni], 0, 0, 0);
            }
        __syncthreads();
    }

#pragma unroll
    for (int reg = 0; reg < 4; reg++) {
        const float inv = 1.0f / lrow[reg];
        const int row = qt * 64 + wid * 16 + lg * 4 + reg;
#pragma unroll
        for (int ni = 0; ni < 4; ni++)
            c[base + (size_t)row * H_ + ni * 16 + lc] = f2bf(o[ni][reg] * inv);
    }
}

// ---------------------------------------------------------------------------
extern "C" void kernel_launch(void* const* d_in, const int* in_sizes, int n_in,
                              void* d_out, int out_size, void* d_ws, size_t ws_size,
                              hipStream_t stream)
{
    const float* Q  = (const float*)d_in[0];
    const float* K  = (const float*)d_in[1];
    const float* V  = (const float*)d_in[2];
    const float* Wq = (const float*)d_in[3];
    const float* Wk = (const float*)d_in[4];
    const float* Wv = (const float*)d_in[5];
    const float* Wo = (const float*)d_in[6];

    unsigned short* qb = (unsigned short*)d_ws;
    unsigned short* kb = qb + (size_t)M_ * H_;
    unsigned short* vb = kb + (size_t)M_ * H_;
    unsigned short* cb = vb + (size_t)M_ * H_;   // doubles as bf16-X staging
    unsigned short* wq = cb + (size_t)M_ * H_;
    unsigned short* wk = wq + (size_t)H_ * H_;
    unsigned short* wv = wk + (size_t)H_ * H_;
    unsigned short* wo = wv + (size_t)H_ * H_;

    const int nX4 = M_ * H_ / 4;   // 1572864
    const int nW4 = H_ * H_ / 4;   // 147456
    const int bX  = (nX4 + 255) / 256;
    const int bW  = (nW4 + 255) / 256;
    const float SC = 0.125f * 1.44269504089f;   // log2(e)/sqrt(DK)

    cvt_bf16<<<bW, 256, 0, stream>>>(Wq, wq, nW4, SC);
    cvt_bf16<<<bW, 256, 0, stream>>>(Wk, wk, nW4, 1.f);
    cvt_bf16<<<bW, 256, 0, stream>>>(Wv, wv, nW4, 1.f);
    cvt_bf16<<<bW, 256, 0, stream>>>(Wo, wo, nW4, 1.f);

    const dim3 gg(M_ / 128, H_ / 128);   // 64 x 6

    cvt_bf16<<<bX, 256, 0, stream>>>(Q, cb, nX4, 1.f);
    gemm_bt<true ><<<gg, 256, 0, stream>>>(cb, wq, qb, M_, H_, H_);
    cvt_bf16<<<bX, 256, 0, stream>>>(K, cb, nX4, 1.f);
    gemm_bt<true ><<<gg, 256, 0, stream>>>(cb, wk, kb, M_, H_, H_);
    cvt_bf16<<<bX, 256, 0, stream>>>(V, cb, nX4, 1.f);
    gemm_bt<true ><<<gg, 256, 0, stream>>>(cb, wv, vb, M_, H_, H_);

    attn<<<dim3(S_ / 64, NH_, B_), 256, 0, stream>>>(qb, kb, vb, cb);

    gemm_bt<false><<<gg, 256, 0, stream>>>(cb, wo, (float*)d_out, M_, H_, H_);
}

// Round 4
// 180.755 us; speedup vs baseline: 1.2997x; 1.2997x over previous
//
#include <hip/hip_runtime.h>
#include <hip/hip_bf16.h>

#define B_   8
#define S_   1024
#define H_   768
#define NH_  12
#define DK_  64
#define M_   (B_ * S_)   // 8192

typedef __attribute__((ext_vector_type(8))) short          short8;
typedef __attribute__((ext_vector_type(8))) unsigned short ushort8;
typedef __attribute__((ext_vector_type(4))) unsigned short ushort4v;
typedef __attribute__((ext_vector_type(4))) float          f32x4;

__device__ __forceinline__ unsigned short f2bf(float x) {
    union { __hip_bfloat16 h; unsigned short u; } r;
    r.h = __float2bfloat16(x);   // RNE, compiler emits packed cvt
    return r.u;
}

// ---------------------------------------------------------------------------
// One-shot convert of the 4 weight matrices to bf16 (Wq pre-scaled by
// log2(e)/sqrt(DK) so attention scores land directly in exp2 domain).
// ---------------------------------------------------------------------------
__global__ __launch_bounds__(256)
void cvt_w(const float* __restrict__ w0, const float* __restrict__ w1,
           const float* __restrict__ w2, const float* __restrict__ w3,
           unsigned short* __restrict__ o0, unsigned short* __restrict__ o1,
           unsigned short* __restrict__ o2, unsigned short* __restrict__ o3)
{
    const int wsel = blockIdx.y;
    const float* src = (wsel == 0) ? w0 : (wsel == 1) ? w1 : (wsel == 2) ? w2 : w3;
    unsigned short* dst = (wsel == 0) ? o0 : (wsel == 1) ? o1 : (wsel == 2) ? o2 : o3;
    const float s = (wsel == 0) ? 0.125f * 1.44269504089f : 1.0f;
    const int i = blockIdx.x * 256 + threadIdx.x;   // float4 index
    const float4 x = ((const float4*)src)[i];
    ushort4v o;
    o[0] = f2bf(x.x * s); o[1] = f2bf(x.y * s);
    o[2] = f2bf(x.z * s); o[3] = f2bf(x.w * s);
    ((ushort4v*)dst)[i] = o;
}

// ---------------------------------------------------------------------------
// y[M,N] = x[M,K] @ W[N,K]^T.  128x128 tile, BK=32, 4 waves x (4x4) frags.
// A: fp32 (converted during staging) or bf16.  W: bf16.  blockIdx.z selects
// one of up to 3 independent (A, W, C) triples (fused QKV projections).
// ---------------------------------------------------------------------------
template<bool A_BF16, bool OUT_BF16>
__global__ __launch_bounds__(256)
void gemm_bt(const void* __restrict__ A0, const void* __restrict__ A1,
             const void* __restrict__ A2,
             const unsigned short* __restrict__ W0,
             const unsigned short* __restrict__ W1,
             const unsigned short* __restrict__ W2,
             void* __restrict__ C0, void* __restrict__ C1, void* __restrict__ C2)
{
    __shared__ unsigned short As[128 * 32];
    __shared__ unsigned short Bs[128 * 32];

    const int tid  = threadIdx.x;
    const int z    = blockIdx.z;
    const int bm   = blockIdx.x, bn = blockIdx.y;
    const int w    = tid >> 6, lane = tid & 63;
    const int lg   = lane >> 4, lc = lane & 15;
    const int wm   = (w >> 1) * 64, wn = (w & 1) * 64;

    const void* Av = (z == 0) ? A0 : (z == 1) ? A1 : A2;
    const unsigned short* Bw = (z == 0) ? W0 : (z == 1) ? W1 : W2;
    void* Cv = (z == 0) ? C0 : (z == 1) ? C1 : C2;

    const float*          Af = (const float*)Av;
    const unsigned short* Ah = (const unsigned short*)Av;

    f32x4 acc[4][4] = {};

    for (int k0 = 0; k0 < H_; k0 += 32) {
        // --- stage A tile 128x32 ---
        if (A_BF16) {
#pragma unroll
            for (int i = 0; i < 2; i++) {
                const int gI = i * 256 + tid;          // 512 ushort8 groups
                const int row = gI >> 2, c8 = (gI & 3) * 8;
                *(ushort8*)&As[row * 32 + c8] =
                    *(const ushort8*)&Ah[(size_t)(bm * 128 + row) * H_ + k0 + c8];
            }
        } else {
#pragma unroll
            for (int i = 0; i < 4; i++) {
                const int gI = i * 256 + tid;          // 1024 float4 groups
                const int row = gI >> 3, c4 = (gI & 7) * 4;
                const float4 x = *(const float4*)&Af[(size_t)(bm * 128 + row) * H_ + k0 + c4];
                ushort4v o4;
                o4[0] = f2bf(x.x); o4[1] = f2bf(x.y);
                o4[2] = f2bf(x.z); o4[3] = f2bf(x.w);
                *(ushort4v*)&As[row * 32 + c4] = o4;
            }
        }
        // --- stage B tile 128x32 (bf16) ---
#pragma unroll
        for (int i = 0; i < 2; i++) {
            const int gI = i * 256 + tid;
            const int row = gI >> 2, c8 = (gI & 3) * 8;
            *(ushort8*)&Bs[row * 32 + c8] =
                *(const ushort8*)&Bw[(size_t)(bn * 128 + row) * H_ + k0 + c8];
        }
        __syncthreads();

        short8 af[4], bfr[4];
#pragma unroll
        for (int mi = 0; mi < 4; mi++)
            af[mi] = *(const short8*)&As[(wm + mi * 16 + lc) * 32 + lg * 8];
#pragma unroll
        for (int ni = 0; ni < 4; ni++)
            bfr[ni] = *(const short8*)&Bs[(wn + ni * 16 + lc) * 32 + lg * 8];
#pragma unroll
        for (int mi = 0; mi < 4; mi++)
#pragma unroll
            for (int ni = 0; ni < 4; ni++)
                acc[mi][ni] = __builtin_amdgcn_mfma_f32_16x16x32_bf16(
                    af[mi], bfr[ni], acc[mi][ni], 0, 0, 0);
        __syncthreads();
    }

#pragma unroll
    for (int mi = 0; mi < 4; mi++)
#pragma unroll
        for (int ni = 0; ni < 4; ni++)
#pragma unroll
            for (int reg = 0; reg < 4; reg++) {
                const int row = bm * 128 + wm + mi * 16 + lg * 4 + reg;
                const int col = bn * 128 + wn + ni * 16 + lc;
                if (OUT_BF16)
                    ((unsigned short*)Cv)[(size_t)row * H_ + col] = f2bf(acc[mi][ni][reg]);
                else
                    ((float*)Cv)[(size_t)row * H_ + col] = acc[mi][ni][reg];
            }
}

// ---------------------------------------------------------------------------
// Flash attention: 1 block = (b, head, 128-row q tile). 4 waves x 32 q-rows.
// Q pre-scaled (via Wq) -> scores in exp2 domain. XOR-swizzled V^T and P.
// K/V staging + barriers amortized over 32 MFMA/iter.
// ---------------------------------------------------------------------------
__global__ __launch_bounds__(256)
void attn(const unsigned short* __restrict__ q,
          const unsigned short* __restrict__ k,
          const unsigned short* __restrict__ v,
          unsigned short* __restrict__ c)
{
    __shared__ unsigned short Ks[64][72];
    __shared__ unsigned short Vt[64][72];    // Vt[d][key ^ ((d>>4)<<4)]
    __shared__ unsigned short Ps[128][72];   // staging for Q, then P tiles

    const int tid  = threadIdx.x;
    const int qt   = blockIdx.x, h = blockIdx.y, b = blockIdx.z;
    const int wid  = tid >> 6;
    const int lane = tid & 63;
    const int lg   = lane >> 4, lc = lane & 15;
    const int r    = tid >> 2;
    const int d0   = (tid & 3) * 16;
    const int g    = tid & 3;
    const size_t base = (size_t)b * S_ * H_ + (size_t)h * DK_;

    // stage Q tile (128 x 64) into Ps, hoist fragments; Ps then holds P
#pragma unroll
    for (int rr = 0; rr < 128; rr += 64) {
        const unsigned short* src = &q[base + (size_t)(qt * 128 + rr + r) * H_ + d0];
        *(ushort8*)&Ps[rr + r][d0]     = *(const ushort8*)src;
        *(ushort8*)&Ps[rr + r][d0 + 8] = *(const ushort8*)(src + 8);
    }
    __syncthreads();
    short8 aq[2][2];
#pragma unroll
    for (int m = 0; m < 2; m++)
#pragma unroll
        for (int ks = 0; ks < 2; ks++)
            aq[m][ks] = *(const short8*)&Ps[wid * 32 + m * 16 + lc][ks * 32 + lg * 8];

    f32x4 o[2][4] = {};
    float mrow[2][4], lrow[2][4];
#pragma unroll
    for (int m = 0; m < 2; m++)
#pragma unroll
        for (int i = 0; i < 4; i++) { mrow[m][i] = -1e30f; lrow[m][i] = 0.f; }

    for (int kt = 0; kt < S_ / 64; kt++) {
        // stage K tile + transposed V tile (conflict-free swizzle)
        {
            const unsigned short* ksrc = &k[base + (size_t)(kt * 64 + r) * H_ + d0];
            *(ushort8*)&Ks[r][d0]     = *(const ushort8*)ksrc;
            *(ushort8*)&Ks[r][d0 + 8] = *(const ushort8*)(ksrc + 8);
            const unsigned short* vsrc = &v[base + (size_t)(kt * 64 + r) * H_ + d0];
            const ushort8 v0 = *(const ushort8*)vsrc;
            const ushort8 v1 = *(const ushort8*)(vsrc + 8);
            const int colv = r ^ (g << 4);
#pragma unroll
            for (int j = 0; j < 8; j++) Vt[d0 + j][colv]     = v0[j];
#pragma unroll
            for (int j = 0; j < 8; j++) Vt[d0 + 8 + j][colv] = v1[j];
        }
        __syncthreads();

        // S = Q K^T  (wave's 32 q-rows x 64 keys), exp2-domain scaled
        f32x4 s[2][4] = {};
#pragma unroll
        for (int ni = 0; ni < 4; ni++) {
            const short8 bk0 = *(const short8*)&Ks[ni * 16 + lc][lg * 8];
            const short8 bk1 = *(const short8*)&Ks[ni * 16 + lc][32 + lg * 8];
            s[0][ni] = __builtin_amdgcn_mfma_f32_16x16x32_bf16(aq[0][0], bk0, s[0][ni], 0, 0, 0);
            s[0][ni] = __builtin_amdgcn_mfma_f32_16x16x32_bf16(aq[0][1], bk1, s[0][ni], 0, 0, 0);
            s[1][ni] = __builtin_amdgcn_mfma_f32_16x16x32_bf16(aq[1][0], bk0, s[1][ni], 0, 0, 0);
            s[1][ni] = __builtin_amdgcn_mfma_f32_16x16x32_bf16(aq[1][1], bk1, s[1][ni], 0, 0, 0);
        }

        // online softmax (rows at m*16 + lg*4 + reg, key-cols at ni*16 + lc)
#pragma unroll
        for (int m = 0; m < 2; m++)
#pragma unroll
            for (int reg = 0; reg < 4; reg++) {
                float pm = fmaxf(fmaxf(s[m][0][reg], s[m][1][reg]),
                                 fmaxf(s[m][2][reg], s[m][3][reg]));
#pragma unroll
                for (int d = 1; d < 16; d <<= 1)
                    pm = fmaxf(pm, __shfl_xor(pm, d, 64));
                const float mnew  = fmaxf(mrow[m][reg], pm);
                const float scale = exp2f(mrow[m][reg] - mnew);
                float psum = 0.f;
#pragma unroll
                for (int ni = 0; ni < 4; ni++) {
                    const float p = exp2f(s[m][ni][reg] - mnew);
                    s[m][ni][reg] = p; psum += p;
                }
#pragma unroll
                for (int d = 1; d < 16; d <<= 1)
                    psum += __shfl_xor(psum, d, 64);
                lrow[m][reg] = lrow[m][reg] * scale + psum;
                mrow[m][reg] = mnew;
                o[m][0][reg] *= scale; o[m][1][reg] *= scale;
                o[m][2][reg] *= scale; o[m][3][reg] *= scale;
            }

        // P -> LDS, swizzled; wave-local 32-row region
#pragma unroll
        for (int m = 0; m < 2; m++)
#pragma unroll
            for (int ni = 0; ni < 4; ni++)
#pragma unroll
                for (int reg = 0; reg < 4; reg++)
                    Ps[wid * 32 + m * 16 + lg * 4 + reg][(ni * 16 + lc) ^ (lg << 4)] =
                        f2bf(s[m][ni][reg]);

        short8 pa[2][2];
#pragma unroll
        for (int m = 0; m < 2; m++)
#pragma unroll
            for (int ks = 0; ks < 2; ks++)
                pa[m][ks] = *(const short8*)
                    &Ps[wid * 32 + m * 16 + lc][(ks * 32 + lg * 8) ^ ((lc >> 2) << 4)];
#pragma unroll
        for (int ni = 0; ni < 4; ni++)
#pragma unroll
            for (int ks = 0; ks < 2; ks++) {
                const short8 bv = *(const short8*)
                    &Vt[ni * 16 + lc][(ks * 32 + lg * 8) ^ (ni << 4)];
                o[0][ni] = __builtin_amdgcn_mfma_f32_16x16x32_bf16(pa[0][ks], bv, o[0][ni], 0, 0, 0);
                o[1][ni] = __builtin_amdgcn_mfma_f32_16x16x32_bf16(pa[1][ks], bv, o[1][ni], 0, 0, 0);
            }
        __syncthreads();
    }

    // write context (bf16) to c[B,S,H]
#pragma unroll
    for (int m = 0; m < 2; m++)
#pragma unroll
        for (int reg = 0; reg < 4; reg++) {
            const float inv = 1.0f / lrow[m][reg];
            const int row = qt * 128 + wid * 32 + m * 16 + lg * 4 + reg;
#pragma unroll
            for (int ni = 0; ni < 4; ni++)
                c[base + (size_t)row * H_ + ni * 16 + lc] = f2bf(o[m][ni][reg] * inv);
        }
}

// ---------------------------------------------------------------------------
extern "C" void kernel_launch(void* const* d_in, const int* in_sizes, int n_in,
                              void* d_out, int out_size, void* d_ws, size_t ws_size,
                              hipStream_t stream)
{
    const float* Q  = (const float*)d_in[0];
    const float* K  = (const float*)d_in[1];
    const float* V  = (const float*)d_in[2];
    const float* Wq = (const float*)d_in[3];
    const float* Wk = (const float*)d_in[4];
    const float* Wv = (const float*)d_in[5];
    const float* Wo = (const float*)d_in[6];

    unsigned short* qb = (unsigned short*)d_ws;
    unsigned short* kb = qb + (size_t)M_ * H_;
    unsigned short* vb = kb + (size_t)M_ * H_;
    unsigned short* cb = vb + (size_t)M_ * H_;
    unsigned short* wq = cb + (size_t)M_ * H_;
    unsigned short* wk = wq + (size_t)H_ * H_;
    unsigned short* wv = wk + (size_t)H_ * H_;
    unsigned short* wo = wv + (size_t)H_ * H_;

    // 1. convert all 4 weights (Wq pre-scaled by log2(e)/sqrt(DK))
    cvt_w<<<dim3(H_ * H_ / 4 / 256, 4), 256, 0, stream>>>(
        Wq, Wk, Wv, Wo, wq, wk, wv, wo);

    // 2. fused Q/K/V projections: grid.z selects the (X, W, out) triple
    gemm_bt<false, true><<<dim3(M_ / 128, H_ / 128, 3), 256, 0, stream>>>(
        Q, K, V, wq, wk, wv, qb, kb, vb);

    // 3. attention
    attn<<<dim3(S_ / 128, NH_, B_), 256, 0, stream>>>(qb, kb, vb, cb);

    // 4. output projection (bf16 A, fp32 out)
    gemm_bt<true, false><<<dim3(M_ / 128, H_ / 128, 1), 256, 0, stream>>>(
        cb, cb, cb, wo, wo, wo, d_out, d_out, d_out);
}

// Round 6
// 155.341 us; speedup vs baseline: 1.5124x; 1.1636x over previous
//
#include <hip/hip_runtime.h>
#include <hip/hip_bf16.h>

#define B_   8
#define S_   1024
#define H_   768
#define NH_  12
#define DK_  64
#define M_   (B_ * S_)   // 8192

typedef __attribute__((ext_vector_type(8))) short          short8;
typedef __attribute__((ext_vector_type(8))) unsigned short ushort8;
typedef __attribute__((ext_vector_type(4))) unsigned short ushort4v;
typedef __attribute__((ext_vector_type(4))) float          f32x4;

__device__ __forceinline__ unsigned short f2bf(float x) {
    union { __hip_bfloat16 h; unsigned short u; } r;
    r.h = __float2bfloat16(x);
    return r.u;
}

__device__ __forceinline__ unsigned cvtpk_bf16(float lo, float hi) {
    unsigned r;
    asm("v_cvt_pk_bf16_f32 %0, %1, %2" : "=v"(r) : "v"(lo), "v"(hi));
    return r;
}

// ---------------------------------------------------------------------------
// One-shot convert of the 4 weight matrices to bf16 (Wq pre-scaled by
// log2(e)/sqrt(DK) so attention scores land directly in exp2 domain).
// ---------------------------------------------------------------------------
__global__ __launch_bounds__(256)
void cvt_w(const float* __restrict__ w0, const float* __restrict__ w1,
           const float* __restrict__ w2, const float* __restrict__ w3,
           unsigned short* __restrict__ o0, unsigned short* __restrict__ o1,
           unsigned short* __restrict__ o2, unsigned short* __restrict__ o3)
{
    const int wsel = blockIdx.y;
    const float* src = (wsel == 0) ? w0 : (wsel == 1) ? w1 : (wsel == 2) ? w2 : w3;
    unsigned short* dst = (wsel == 0) ? o0 : (wsel == 1) ? o1 : (wsel == 2) ? o2 : o3;
    const float s = (wsel == 0) ? 0.125f * 1.44269504089f : 1.0f;
    const int i = blockIdx.x * 256 + threadIdx.x;
    const float4 x = ((const float4*)src)[i];
    ushort4v o;
    o[0] = f2bf(x.x * s); o[1] = f2bf(x.y * s);
    o[2] = f2bf(x.z * s); o[3] = f2bf(x.w * s);
    ((ushort4v*)dst)[i] = o;
}

// ---------------------------------------------------------------------------
// y[M,N] = x[M,K] @ W[N,K]^T.  128x128 tile, BK=32, 4 waves x (4x4) frags.
// blockIdx.z selects one of up to 3 (A, W, C) triples (fused QKV).
// ---------------------------------------------------------------------------
template<bool A_BF16, bool OUT_BF16>
__global__ __launch_bounds__(256)
void gemm_bt(const void* __restrict__ A0, const void* __restrict__ A1,
             const void* __restrict__ A2,
             const unsigned short* __restrict__ W0,
             const unsigned short* __restrict__ W1,
             const unsigned short* __restrict__ W2,
             void* __restrict__ C0, void* __restrict__ C1, void* __restrict__ C2)
{
    __shared__ unsigned short As[128 * 32];
    __shared__ unsigned short Bs[128 * 32];

    const int tid  = threadIdx.x;
    const int z    = blockIdx.z;
    const int bm   = blockIdx.x, bn = blockIdx.y;
    const int w    = tid >> 6, lane = tid & 63;
    const int lg   = lane >> 4, lc = lane & 15;
    const int wm   = (w >> 1) * 64, wn = (w & 1) * 64;

    const void* Av = (z == 0) ? A0 : (z == 1) ? A1 : A2;
    const unsigned short* Bw = (z == 0) ? W0 : (z == 1) ? W1 : W2;
    void* Cv = (z == 0) ? C0 : (z == 1) ? C1 : C2;

    const float*          Af = (const float*)Av;
    const unsigned short* Ah = (const unsigned short*)Av;

    f32x4 acc[4][4] = {};

    for (int k0 = 0; k0 < H_; k0 += 32) {
        if (A_BF16) {
#pragma unroll
            for (int i = 0; i < 2; i++) {
                const int gI = i * 256 + tid;
                const int row = gI >> 2, c8 = (gI & 3) * 8;
                *(ushort8*)&As[row * 32 + c8] =
                    *(const ushort8*)&Ah[(size_t)(bm * 128 + row) * H_ + k0 + c8];
            }
        } else {
#pragma unroll
            for (int i = 0; i < 4; i++) {
                const int gI = i * 256 + tid;
                const int row = gI >> 3, c4 = (gI & 7) * 4;
                const float4 x = *(const float4*)&Af[(size_t)(bm * 128 + row) * H_ + k0 + c4];
                ushort4v o4;
                o4[0] = f2bf(x.x); o4[1] = f2bf(x.y);
                o4[2] = f2bf(x.z); o4[3] = f2bf(x.w);
                *(ushort4v*)&As[row * 32 + c4] = o4;
            }
        }
#pragma unroll
        for (int i = 0; i < 2; i++) {
            const int gI = i * 256 + tid;
            const int row = gI >> 2, c8 = (gI & 3) * 8;
            *(ushort8*)&Bs[row * 32 + c8] =
                *(const ushort8*)&Bw[(size_t)(bn * 128 + row) * H_ + k0 + c8];
        }
        __syncthreads();

        short8 af[4], bfr[4];
#pragma unroll
        for (int mi = 0; mi < 4; mi++)
            af[mi] = *(const short8*)&As[(wm + mi * 16 + lc) * 32 + lg * 8];
#pragma unroll
        for (int ni = 0; ni < 4; ni++)
            bfr[ni] = *(const short8*)&Bs[(wn + ni * 16 + lc) * 32 + lg * 8];
#pragma unroll
        for (int mi = 0; mi < 4; mi++)
#pragma unroll
            for (int ni = 0; ni < 4; ni++)
                acc[mi][ni] = __builtin_amdgcn_mfma_f32_16x16x32_bf16(
                    af[mi], bfr[ni], acc[mi][ni], 0, 0, 0);
        __syncthreads();
    }

#pragma unroll
    for (int mi = 0; mi < 4; mi++)
#pragma unroll
        for (int ni = 0; ni < 4; ni++)
#pragma unroll
            for (int reg = 0; reg < 4; reg++) {
                const int row = bm * 128 + wm + mi * 16 + lg * 4 + reg;
                const int col = bn * 128 + wn + ni * 16 + lc;
                if (OUT_BF16)
                    ((unsigned short*)Cv)[(size_t)row * H_ + col] = f2bf(acc[mi][ni][reg]);
                else
                    ((float*)Cv)[(size_t)row * H_ + col] = acc[mi][ni][reg];
            }
}

// ---------------------------------------------------------------------------
// Flash attention v2: swapped QK^T (S^T layout: q = lane&15, key in-register)
// -> in-register softmax (2 shuffles/row-group), P packed via cvt_pk and
// exchanged to PV A-fragments with double-shuffle + post-select (the register
// selection MUST happen on the target lane: source lanes serve two targets
// needing different ni blocks in the same shuffle).
// ---------------------------------------------------------------------------
__global__ __launch_bounds__(256)
void attn(const unsigned short* __restrict__ q,
          const unsigned short* __restrict__ k,
          const unsigned short* __restrict__ v,
          unsigned short* __restrict__ c)
{
    __shared__ unsigned short Ks[64][72];
    __shared__ unsigned short Vt[64][72];    // Vt[d][key ^ ((d>>4)<<4)]

    const int tid  = threadIdx.x;
    const int qt   = blockIdx.x, h = blockIdx.y, b = blockIdx.z;
    const int wid  = tid >> 6;
    const int lane = tid & 63;
    const int lg   = lane >> 4, lc = lane & 15;
    const int r    = tid >> 2;
    const int d0   = (tid & 3) * 16;
    const int g    = tid & 3;
    const size_t base = (size_t)b * S_ * H_ + (size_t)h * DK_;

    // Q fragments straight from global (q pre-scaled by log2e/sqrt(dk) via Wq)
    short8 aq[2][2];
#pragma unroll
    for (int m = 0; m < 2; m++)
#pragma unroll
        for (int ks = 0; ks < 2; ks++)
            aq[m][ks] = *(const short8*)
                &q[base + (size_t)(qt * 128 + wid * 32 + m * 16 + lc) * H_ + ks * 32 + lg * 8];

    f32x4 o[2][4] = {};
    float mrow[2] = {-1e30f, -1e30f}, lrow[2] = {0.f, 0.f};

    for (int kt = 0; kt < S_ / 64; kt++) {
        // stage K tile + transposed V tile (conflict-free swizzle)
        {
            const unsigned short* ksrc = &k[base + (size_t)(kt * 64 + r) * H_ + d0];
            *(ushort8*)&Ks[r][d0]     = *(const ushort8*)ksrc;
            *(ushort8*)&Ks[r][d0 + 8] = *(const ushort8*)(ksrc + 8);
            const unsigned short* vsrc = &v[base + (size_t)(kt * 64 + r) * H_ + d0];
            const ushort8 v0 = *(const ushort8*)vsrc;
            const ushort8 v1 = *(const ushort8*)(vsrc + 8);
            const int colv = r ^ (g << 4);
#pragma unroll
            for (int j = 0; j < 8; j++) Vt[d0 + j][colv]     = v0[j];
#pragma unroll
            for (int j = 0; j < 8; j++) Vt[d0 + 8 + j][colv] = v1[j];
        }
        __syncthreads();

        // S^T = K Q^T : lane holds S[key = 16ni+4lg+reg][q = lc] (per m-block)
        f32x4 st[2][4] = {};
#pragma unroll
        for (int ni = 0; ni < 4; ni++)
#pragma unroll
            for (int ks = 0; ks < 2; ks++) {
                const short8 bk = *(const short8*)&Ks[ni * 16 + lc][ks * 32 + lg * 8];
                st[0][ni] = __builtin_amdgcn_mfma_f32_16x16x32_bf16(bk, aq[0][ks], st[0][ni], 0, 0, 0);
                st[1][ni] = __builtin_amdgcn_mfma_f32_16x16x32_bf16(bk, aq[1][ks], st[1][ni], 0, 0, 0);
            }

        // in-register online softmax + P pack (exp2 domain)
        unsigned pw[2][4][2];
#pragma unroll
        for (int m = 0; m < 2; m++) {
            float pm = st[m][0][0];
#pragma unroll
            for (int ni = 0; ni < 4; ni++)
#pragma unroll
                for (int reg = 0; reg < 4; reg++)
                    pm = fmaxf(pm, st[m][ni][reg]);
            pm = fmaxf(pm, __shfl_xor(pm, 16, 64));
            pm = fmaxf(pm, __shfl_xor(pm, 32, 64));
            const float mnew  = fmaxf(mrow[m], pm);
            const float scale = exp2f(mrow[m] - mnew);
            float psum = 0.f;
#pragma unroll
            for (int ni = 0; ni < 4; ni++)
#pragma unroll
                for (int reg = 0; reg < 4; reg++) {
                    const float p = exp2f(st[m][ni][reg] - mnew);
                    st[m][ni][reg] = p; psum += p;
                }
            psum += __shfl_xor(psum, 16, 64);
            psum += __shfl_xor(psum, 32, 64);
            lrow[m] = lrow[m] * scale + psum;
            mrow[m] = mnew;

            // broadcast scale into o-layout rows (row = 4*lg + reg)
            float scr[4];
#pragma unroll
            for (int reg = 0; reg < 4; reg++)
                scr[reg] = __shfl(scale, lg * 4 + reg, 64);
#pragma unroll
            for (int ni = 0; ni < 4; ni++)
#pragma unroll
                for (int reg = 0; reg < 4; reg++)
                    o[m][ni][reg] *= scr[reg];

            // pack P pairs: pw[m][ni][w] = bf16{key 16ni+4lg+2w (lo), +2w+1 (hi)}
#pragma unroll
            for (int ni = 0; ni < 4; ni++) {
                pw[m][ni][0] = cvtpk_bf16(st[m][ni][0], st[m][ni][1]);
                pw[m][ni][1] = cvtpk_bf16(st[m][ni][2], st[m][ni][3]);
            }
        }

        // exchange P^T -> PV A-fragments.
        // Target lane (lc,lg), word t (keys ks*32+lg*8+2t,+2t+1, q=lc) comes
        // from source lane lc + 16*(2*(lg&1) + (t>>1)), register
        // pw[2ks + (lg>>1)][t&1].  ni depends on TARGET lg -> shuffle both
        // candidates, select after.
        const int sl0 = lc + ((lg & 1) << 5);   // for t = 0,1
        const int sl1 = sl0 + 16;               // for t = 2,3
        const bool hi = (lg >> 1) != 0;
        short8 pa[2][2];
#pragma unroll
        for (int m = 0; m < 2; m++)
#pragma unroll
            for (int ks = 0; ks < 2; ks++) {
                const unsigned lo0 = pw[m][2 * ks][0],     lo1 = pw[m][2 * ks][1];
                const unsigned hi0 = pw[m][2 * ks + 1][0], hi1 = pw[m][2 * ks + 1][1];
                union { unsigned u[4]; short8 s8; } pk;
                const unsigned a0l = __shfl(lo0, sl0, 64), a0h = __shfl(hi0, sl0, 64);
                const unsigned a1l = __shfl(lo1, sl0, 64), a1h = __shfl(hi1, sl0, 64);
                const unsigned a2l = __shfl(lo0, sl1, 64), a2h = __shfl(hi0, sl1, 64);
                const unsigned a3l = __shfl(lo1, sl1, 64), a3h = __shfl(hi1, sl1, 64);
                pk.u[0] = hi ? a0h : a0l;
                pk.u[1] = hi ? a1h : a1l;
                pk.u[2] = hi ? a2h : a2l;
                pk.u[3] = hi ? a3h : a3l;
                pa[m][ks] = pk.s8;
            }

        // O += P V
#pragma unroll
        for (int ni = 0; ni < 4; ni++)
#pragma unroll
            for (int ks = 0; ks < 2; ks++) {
                const short8 bv = *(const short8*)
                    &Vt[ni * 16 + lc][(ks * 32 + lg * 8) ^ (ni << 4)];
                o[0][ni] = __builtin_amdgcn_mfma_f32_16x16x32_bf16(pa[0][ks], bv, o[0][ni], 0, 0, 0);
                o[1][ni] = __builtin_amdgcn_mfma_f32_16x16x32_bf16(pa[1][ks], bv, o[1][ni], 0, 0, 0);
            }
        __syncthreads();
    }

    // write context (bf16); o rows = 4lg+reg need 1/lrow from lane q=row
#pragma unroll
    for (int m = 0; m < 2; m++) {
        const float iv = 1.0f / lrow[m];
#pragma unroll
        for (int reg = 0; reg < 4; reg++) {
            const float ivr = __shfl(iv, lg * 4 + reg, 64);
            const int row = qt * 128 + wid * 32 + m * 16 + lg * 4 + reg;
#pragma unroll
            for (int ni = 0; ni < 4; ni++)
                c[base + (size_t)row * H_ + ni * 16 + lc] = f2bf(o[m][ni][reg] * ivr);
        }
    }
}

// ---------------------------------------------------------------------------
extern "C" void kernel_launch(void* const* d_in, const int* in_sizes, int n_in,
                              void* d_out, int out_size, void* d_ws, size_t ws_size,
                              hipStream_t stream)
{
    const float* Q  = (const float*)d_in[0];
    const float* K  = (const float*)d_in[1];
    const float* V  = (const float*)d_in[2];
    const float* Wq = (const float*)d_in[3];
    const float* Wk = (const float*)d_in[4];
    const float* Wv = (const float*)d_in[5];
    const float* Wo = (const float*)d_in[6];

    unsigned short* qb = (unsigned short*)d_ws;
    unsigned short* kb = qb + (size_t)M_ * H_;
    unsigned short* vb = kb + (size_t)M_ * H_;
    unsigned short* cb = vb + (size_t)M_ * H_;
    unsigned short* wq = cb + (size_t)M_ * H_;
    unsigned short* wk = wq + (size_t)H_ * H_;
    unsigned short* wv = wk + (size_t)H_ * H_;
    unsigned short* wo = wv + (size_t)H_ * H_;

    cvt_w<<<dim3(H_ * H_ / 4 / 256, 4), 256, 0, stream>>>(
        Wq, Wk, Wv, Wo, wq, wk, wv, wo);

    gemm_bt<false, true><<<dim3(M_ / 128, H_ / 128, 3), 256, 0, stream>>>(
        Q, K, V, wq, wk, wv, qb, kb, vb);

    attn<<<dim3(S_ / 128, NH_, B_), 256, 0, stream>>>(qb, kb, vb, cb);

    gemm_bt<true, false><<<dim3(M_ / 128, H_ / 128, 1), 256, 0, stream>>>(
        cb, cb, cb, wo, wo, wo, d_out, d_out, d_out);
}

// Round 7
// 150.659 us; speedup vs baseline: 1.5594x; 1.0311x over previous
//
#include <hip/hip_runtime.h>
#include <hip/hip_bf16.h>

#define B_   8
#define S_   1024
#define H_   768
#define NH_  12
#define DK_  64
#define M_   (B_ * S_)   // 8192

typedef __attribute__((ext_vector_type(8))) short          short8;
typedef __attribute__((ext_vector_type(8))) unsigned short ushort8;
typedef __attribute__((ext_vector_type(4))) unsigned short ushort4v;
typedef __attribute__((ext_vector_type(4))) float          f32x4;

__device__ __forceinline__ unsigned short f2bf(float x) {
    union { __hip_bfloat16 h; unsigned short u; } r;
    r.h = __float2bfloat16(x);
    return r.u;
}

__device__ __forceinline__ unsigned cvtpk_bf16(float lo, float hi) {
    unsigned r;
    asm("v_cvt_pk_bf16_f32 %0, %1, %2" : "=v"(r) : "v"(lo), "v"(hi));
    return r;
}

// ---------------------------------------------------------------------------
// One-shot convert of the 4 weight matrices to bf16 (Wq pre-scaled by
// log2(e)/sqrt(DK) so attention scores land directly in exp2 domain).
// ---------------------------------------------------------------------------
__global__ __launch_bounds__(256)
void cvt_w(const float* __restrict__ w0, const float* __restrict__ w1,
           const float* __restrict__ w2, const float* __restrict__ w3,
           unsigned short* __restrict__ o0, unsigned short* __restrict__ o1,
           unsigned short* __restrict__ o2, unsigned short* __restrict__ o3)
{
    const int wsel = blockIdx.y;
    const float* src = (wsel == 0) ? w0 : (wsel == 1) ? w1 : (wsel == 2) ? w2 : w3;
    unsigned short* dst = (wsel == 0) ? o0 : (wsel == 1) ? o1 : (wsel == 2) ? o2 : o3;
    const float s = (wsel == 0) ? 0.125f * 1.44269504089f : 1.0f;
    const int i = blockIdx.x * 256 + threadIdx.x;
    const float4 x = ((const float4*)src)[i];
    ushort4v o;
    o[0] = f2bf(x.x * s); o[1] = f2bf(x.y * s);
    o[2] = f2bf(x.z * s); o[3] = f2bf(x.w * s);
    ((ushort4v*)dst)[i] = o;
}

// ---------------------------------------------------------------------------
// y[M,N] = x[M,K] @ W[N,K]^T.  128x128 tile, BK=32, 4 waves x (4x4) frags.
// blockIdx.z selects one of up to 3 (A, W, C) triples (fused QKV).
// ---------------------------------------------------------------------------
template<bool A_BF16, bool OUT_BF16>
__global__ __launch_bounds__(256)
void gemm_bt(const void* __restrict__ A0, const void* __restrict__ A1,
             const void* __restrict__ A2,
             const unsigned short* __restrict__ W0,
             const unsigned short* __restrict__ W1,
             const unsigned short* __restrict__ W2,
             void* __restrict__ C0, void* __restrict__ C1, void* __restrict__ C2)
{
    __shared__ unsigned short As[128 * 32];
    __shared__ unsigned short Bs[128 * 32];

    const int tid  = threadIdx.x;
    const int z    = blockIdx.z;
    const int bm   = blockIdx.x, bn = blockIdx.y;
    const int w    = tid >> 6, lane = tid & 63;
    const int lg   = lane >> 4, lc = lane & 15;
    const int wm   = (w >> 1) * 64, wn = (w & 1) * 64;

    const void* Av = (z == 0) ? A0 : (z == 1) ? A1 : A2;
    const unsigned short* Bw = (z == 0) ? W0 : (z == 1) ? W1 : W2;
    void* Cv = (z == 0) ? C0 : (z == 1) ? C1 : C2;

    const float*          Af = (const float*)Av;
    const unsigned short* Ah = (const unsigned short*)Av;

    f32x4 acc[4][4] = {};

    for (int k0 = 0; k0 < H_; k0 += 32) {
        if (A_BF16) {
#pragma unroll
            for (int i = 0; i < 2; i++) {
                const int gI = i * 256 + tid;
                const int row = gI >> 2, c8 = (gI & 3) * 8;
                *(ushort8*)&As[row * 32 + c8] =
                    *(const ushort8*)&Ah[(size_t)(bm * 128 + row) * H_ + k0 + c8];
            }
        } else {
#pragma unroll
            for (int i = 0; i < 4; i++) {
                const int gI = i * 256 + tid;
                const int row = gI >> 3, c4 = (gI & 7) * 4;
                const float4 x = *(const float4*)&Af[(size_t)(bm * 128 + row) * H_ + k0 + c4];
                ushort4v o4;
                o4[0] = f2bf(x.x); o4[1] = f2bf(x.y);
                o4[2] = f2bf(x.z); o4[3] = f2bf(x.w);
                *(ushort4v*)&As[row * 32 + c4] = o4;
            }
        }
#pragma unroll
        for (int i = 0; i < 2; i++) {
            const int gI = i * 256 + tid;
            const int row = gI >> 2, c8 = (gI & 3) * 8;
            *(ushort8*)&Bs[row * 32 + c8] =
                *(const ushort8*)&Bw[(size_t)(bn * 128 + row) * H_ + k0 + c8];
        }
        __syncthreads();

        short8 af[4], bfr[4];
#pragma unroll
        for (int mi = 0; mi < 4; mi++)
            af[mi] = *(const short8*)&As[(wm + mi * 16 + lc) * 32 + lg * 8];
#pragma unroll
        for (int ni = 0; ni < 4; ni++)
            bfr[ni] = *(const short8*)&Bs[(wn + ni * 16 + lc) * 32 + lg * 8];
#pragma unroll
        for (int mi = 0; mi < 4; mi++)
#pragma unroll
            for (int ni = 0; ni < 4; ni++)
                acc[mi][ni] = __builtin_amdgcn_mfma_f32_16x16x32_bf16(
                    af[mi], bfr[ni], acc[mi][ni], 0, 0, 0);
        __syncthreads();
    }

#pragma unroll
    for (int mi = 0; mi < 4; mi++)
#pragma unroll
        for (int ni = 0; ni < 4; ni++)
#pragma unroll
            for (int reg = 0; reg < 4; reg++) {
                const int row = bm * 128 + wm + mi * 16 + lg * 4 + reg;
                const int col = bn * 128 + wn + ni * 16 + lc;
                if (OUT_BF16)
                    ((unsigned short*)Cv)[(size_t)row * H_ + col] = f2bf(acc[mi][ni][reg]);
                else
                    ((float*)Cv)[(size_t)row * H_ + col] = acc[mi][ni][reg];
            }
}

// ---------------------------------------------------------------------------
// Flash attention v3: swapped QK^T + in-register softmax (round 6) plus:
//  - double-buffered K/V with EARLY global-load issue (latency hides under
//    the previous tile's compute), one barrier per iter
//  - defer-rescale (THR=8, exp2 domain): skip O-rescale unless a row max
//    grew by > 8 (wave-uniform branch)
//  - s_setprio(1) around MFMA clusters
// ---------------------------------------------------------------------------
__global__ __launch_bounds__(256)
void attn(const unsigned short* __restrict__ q,
          const unsigned short* __restrict__ k,
          const unsigned short* __restrict__ v,
          unsigned short* __restrict__ c)
{
    __shared__ unsigned short Ks[2][64][72];
    __shared__ unsigned short Vt[2][64][72];   // Vt[buf][d][key ^ ((d>>4)<<4)]

    const int tid  = threadIdx.x;
    const int qt   = blockIdx.x, h = blockIdx.y, b = blockIdx.z;
    const int wid  = tid >> 6;
    const int lane = tid & 63;
    const int lg   = lane >> 4, lc = lane & 15;
    const int r    = tid >> 2;
    const int d0   = (tid & 3) * 16;
    const int g    = tid & 3;
    const size_t base = (size_t)b * S_ * H_ + (size_t)h * DK_;
    const int colv = r ^ (g << 4);

    // Q fragments straight from global (q pre-scaled by log2e/sqrt(dk) via Wq)
    short8 aq[2][2];
#pragma unroll
    for (int m = 0; m < 2; m++)
#pragma unroll
        for (int ks = 0; ks < 2; ks++)
            aq[m][ks] = *(const short8*)
                &q[base + (size_t)(qt * 128 + wid * 32 + m * 16 + lc) * H_ + ks * 32 + lg * 8];

    f32x4 o[2][4] = {};
    float mrow[2] = {-1e30f, -1e30f}, lrow[2] = {0.f, 0.f};

    const int NT = S_ / 64;

    // prologue: load + stage tile 0 into buffer 0
    ushort8 kr0, kr1, vr0, vr1;
    {
        const unsigned short* ksrc = &k[base + (size_t)r * H_ + d0];
        const unsigned short* vsrc = &v[base + (size_t)r * H_ + d0];
        kr0 = *(const ushort8*)ksrc; kr1 = *(const ushort8*)(ksrc + 8);
        vr0 = *(const ushort8*)vsrc; vr1 = *(const ushort8*)(vsrc + 8);
    }
    *(ushort8*)&Ks[0][r][d0]     = kr0;
    *(ushort8*)&Ks[0][r][d0 + 8] = kr1;
#pragma unroll
    for (int j = 0; j < 8; j++) Vt[0][d0 + j][colv]     = vr0[j];
#pragma unroll
    for (int j = 0; j < 8; j++) Vt[0][d0 + 8 + j][colv] = vr1[j];
    __syncthreads();

    int cur = 0;
    for (int kt = 0; kt < NT; kt++) {
        const bool more = (kt + 1 < NT);
        // issue next tile's global loads NOW; latency hides under compute
        if (more) {
            const unsigned short* ksrc = &k[base + (size_t)((kt + 1) * 64 + r) * H_ + d0];
            const unsigned short* vsrc = &v[base + (size_t)((kt + 1) * 64 + r) * H_ + d0];
            kr0 = *(const ushort8*)ksrc; kr1 = *(const ushort8*)(ksrc + 8);
            vr0 = *(const ushort8*)vsrc; vr1 = *(const ushort8*)(vsrc + 8);
        }

        // S^T = K Q^T : lane holds S[key = 16ni+4lg+reg][q = lc] (per m-block)
        f32x4 st[2][4] = {};
        __builtin_amdgcn_s_setprio(1);
#pragma unroll
        for (int ni = 0; ni < 4; ni++)
#pragma unroll
            for (int ks = 0; ks < 2; ks++) {
                const short8 bk = *(const short8*)&Ks[cur][ni * 16 + lc][ks * 32 + lg * 8];
                st[0][ni] = __builtin_amdgcn_mfma_f32_16x16x32_bf16(bk, aq[0][ks], st[0][ni], 0, 0, 0);
                st[1][ni] = __builtin_amdgcn_mfma_f32_16x16x32_bf16(bk, aq[1][ks], st[1][ni], 0, 0, 0);
            }
        __builtin_amdgcn_s_setprio(0);

        // in-register online softmax + P pack (exp2 domain, defer-rescale)
        unsigned pw[2][4][2];
        float pmax[2];
#pragma unroll
        for (int m = 0; m < 2; m++) {
            float pm = st[m][0][0];
#pragma unroll
            for (int ni = 0; ni < 4; ni++)
#pragma unroll
                for (int reg = 0; reg < 4; reg++)
                    pm = fmaxf(pm, st[m][ni][reg]);
            pm = fmaxf(pm, __shfl_xor(pm, 16, 64));
            pm = fmaxf(pm, __shfl_xor(pm, 32, 64));
            pmax[m] = pm;
        }

        // rescale only when some row's max grew by > 8 (wave-uniform branch)
        if (__any((pmax[0] > mrow[0] + 8.f) | (pmax[1] > mrow[1] + 8.f))) {
#pragma unroll
            for (int m = 0; m < 2; m++) {
                const float mnew  = fmaxf(mrow[m], pmax[m]);
                const float scale = exp2f(mrow[m] - mnew);
                lrow[m] *= scale;
                mrow[m]  = mnew;
                float scr[4];
#pragma unroll
                for (int reg = 0; reg < 4; reg++)
                    scr[reg] = __shfl(scale, lg * 4 + reg, 64);
#pragma unroll
                for (int ni = 0; ni < 4; ni++)
#pragma unroll
                    for (int reg = 0; reg < 4; reg++)
                        o[m][ni][reg] *= scr[reg];
            }
        }

#pragma unroll
        for (int m = 0; m < 2; m++) {
            float psum = 0.f;
#pragma unroll
            for (int ni = 0; ni < 4; ni++)
#pragma unroll
                for (int reg = 0; reg < 4; reg++) {
                    const float p = exp2f(st[m][ni][reg] - mrow[m]);
                    st[m][ni][reg] = p; psum += p;
                }
            psum += __shfl_xor(psum, 16, 64);
            psum += __shfl_xor(psum, 32, 64);
            lrow[m] += psum;
#pragma unroll
            for (int ni = 0; ni < 4; ni++) {
                pw[m][ni][0] = cvtpk_bf16(st[m][ni][0], st[m][ni][1]);
                pw[m][ni][1] = cvtpk_bf16(st[m][ni][2], st[m][ni][3]);
            }
        }

        // exchange P^T -> PV A-fragments (double-shuffle + target-side select)
        const int sl0 = lc + ((lg & 1) << 5);
        const int sl1 = sl0 + 16;
        const bool hi = (lg >> 1) != 0;
        short8 pa[2][2];
#pragma unroll
        for (int m = 0; m < 2; m++)
#pragma unroll
            for (int ks = 0; ks < 2; ks++) {
                const unsigned lo0 = pw[m][2 * ks][0],     lo1 = pw[m][2 * ks][1];
                const unsigned hi0 = pw[m][2 * ks + 1][0], hi1 = pw[m][2 * ks + 1][1];
                union { unsigned u[4]; short8 s8; } pk;
                const unsigned a0l = __shfl(lo0, sl0, 64), a0h = __shfl(hi0, sl0, 64);
                const unsigned a1l = __shfl(lo1, sl0, 64), a1h = __shfl(hi1, sl0, 64);
                const unsigned a2l = __shfl(lo0, sl1, 64), a2h = __shfl(hi0, sl1, 64);
                const unsigned a3l = __shfl(lo1, sl1, 64), a3h = __shfl(hi1, sl1, 64);
                pk.u[0] = hi ? a0h : a0l;
                pk.u[1] = hi ? a1h : a1l;
                pk.u[2] = hi ? a2h : a2l;
                pk.u[3] = hi ? a3h : a3l;
                pa[m][ks] = pk.s8;
            }

        // O += P V
        __builtin_amdgcn_s_setprio(1);
#pragma unroll
        for (int ni = 0; ni < 4; ni++)
#pragma unroll
            for (int ks = 0; ks < 2; ks++) {
                const short8 bv = *(const short8*)
                    &Vt[cur][ni * 16 + lc][(ks * 32 + lg * 8) ^ (ni << 4)];
                o[0][ni] = __builtin_amdgcn_mfma_f32_16x16x32_bf16(pa[0][ks], bv, o[0][ni], 0, 0, 0);
                o[1][ni] = __builtin_amdgcn_mfma_f32_16x16x32_bf16(pa[1][ks], bv, o[1][ni], 0, 0, 0);
            }
        __builtin_amdgcn_s_setprio(0);

        // stage next tile into the other buffer (regs already in flight)
        if (more) {
            *(ushort8*)&Ks[cur ^ 1][r][d0]     = kr0;
            *(ushort8*)&Ks[cur ^ 1][r][d0 + 8] = kr1;
#pragma unroll
            for (int j = 0; j < 8; j++) Vt[cur ^ 1][d0 + j][colv]     = vr0[j];
#pragma unroll
            for (int j = 0; j < 8; j++) Vt[cur ^ 1][d0 + 8 + j][colv] = vr1[j];
        }
        __syncthreads();
        cur ^= 1;
    }

    // write context (bf16); o rows = 4lg+reg need 1/lrow from lane q=row
#pragma unroll
    for (int m = 0; m < 2; m++) {
        const float iv = 1.0f / lrow[m];
#pragma unroll
        for (int reg = 0; reg < 4; reg++) {
            const float ivr = __shfl(iv, lg * 4 + reg, 64);
            const int row = qt * 128 + wid * 32 + m * 16 + lg * 4 + reg;
#pragma unroll
            for (int ni = 0; ni < 4; ni++)
                c[base + (size_t)row * H_ + ni * 16 + lc] = f2bf(o[m][ni][reg] * ivr);
        }
    }
}

// ---------------------------------------------------------------------------
extern "C" void kernel_launch(void* const* d_in, const int* in_sizes, int n_in,
                              void* d_out, int out_size, void* d_ws, size_t ws_size,
                              hipStream_t stream)
{
    const float* Q  = (const float*)d_in[0];
    const float* K  = (const float*)d_in[1];
    const float* V  = (const float*)d_in[2];
    const float* Wq = (const float*)d_in[3];
    const float* Wk = (const float*)d_in[4];
    const float* Wv = (const float*)d_in[5];
    const float* Wo = (const float*)d_in[6];

    unsigned short* qb = (unsigned short*)d_ws;
    unsigned short* kb = qb + (size_t)M_ * H_;
    unsigned short* vb = kb + (size_t)M_ * H_;
    unsigned short* cb = vb + (size_t)M_ * H_;
    unsigned short* wq = cb + (size_t)M_ * H_;
    unsigned short* wk = wq + (size_t)H_ * H_;
    unsigned short* wv = wk + (size_t)H_ * H_;
    unsigned short* wo = wv + (size_t)H_ * H_;

    cvt_w<<<dim3(H_ * H_ / 4 / 256, 4), 256, 0, stream>>>(
        Wq, Wk, Wv, Wo, wq, wk, wv, wo);

    gemm_bt<false, true><<<dim3(M_ / 128, H_ / 128, 3), 256, 0, stream>>>(
        Q, K, V, wq, wk, wv, qb, kb, vb);

    attn<<<dim3(S_ / 128, NH_, B_), 256, 0, stream>>>(qb, kb, vb, cb);

    gemm_bt<true, false><<<dim3(M_ / 128, H_ / 128, 1), 256, 0, stream>>>(
        cb, cb, cb, wo, wo, wo, d_out, d_out, d_out);
}